// Round 15
// baseline (292.024 us; speedup 1.0000x reference)
//
#include <hip/hip_runtime.h>

typedef __attribute__((ext_vector_type(8))) short bf16x8;
typedef __attribute__((ext_vector_type(4))) float f32x4;
typedef __attribute__((ext_vector_type(8))) unsigned short us8;
typedef unsigned short u16;
typedef unsigned int u32;

__device__ __forceinline__ u16 f2bf(float f){
  u32 u = __builtin_bit_cast(u32, f);
  u32 r = (u + 0x7fffu + ((u >> 16) & 1u)) >> 16;
  return (u16)r;
}

#define ASYNC_CP16(gp, lp) __builtin_amdgcn_global_load_lds( \
    (__attribute__((address_space(1))) void*)(gp), \
    (__attribute__((address_space(3))) void*)(lp), 16, 0, 0)

// upper-triangular 128x128 tile table for the symmetric Gram (4x4 tiles)
__device__ const int d_rt[10] = {0,0,0,0,1,1,1,2,2,3};
__device__ const int d_ct[10] = {0,1,2,3,1,2,3,2,3,3};

// ---------------------------------------------------------------------------
// Kernel 1: GroupNorm stats + x -> bf16 conversion.
// ---------------------------------------------------------------------------
__global__ __launch_bounds__(256) void k_stats(const float* __restrict__ x,
    const float* __restrict__ gnw, const float* __restrict__ gnb,
    u16* __restrict__ xb, float* __restrict__ a, float* __restrict__ cv,
    float* __restrict__ sx)
{
  int b = blockIdx.x >> 5;
  int g = blockIdx.x & 31;
  int tid = threadIdx.x;
  int cl = tid >> 4;
  int l16 = tid & 15;
  int c = g * 16 + cl;
  const float* xp = x + ((long)(b * 512 + c)) * 4096;
  u16* xbp = xb + ((long)(b * 512 + c)) * 4096;
  float s = 0.f, sq = 0.f;
  for (int it = 0; it < 64; ++it) {
    int i4 = it * 16 + l16;
    float4 v = *(const float4*)(xp + i4 * 4);
    s  += v.x + v.y + v.z + v.w;
    sq += v.x * v.x + v.y * v.y + v.z * v.z + v.w * v.w;
    ushort4 o;
    o.x = f2bf(v.x); o.y = f2bf(v.y); o.z = f2bf(v.z); o.w = f2bf(v.w);
    *(ushort4*)(xbp + i4 * 4) = o;
  }
  for (int off = 8; off; off >>= 1) { s += __shfl_xor(s, off); sq += __shfl_xor(sq, off); }
  __shared__ float chS[16], chQ[16];
  if (l16 == 0) { chS[cl] = s; chQ[cl] = sq; }
  __syncthreads();
  if (tid < 16) {
    float S = 0.f, Q = 0.f;
    for (int j = 0; j < 16; ++j) { S += chS[j]; Q += chQ[j]; }
    float mean = S * (1.f / 65536.f);
    float var  = Q * (1.f / 65536.f) - mean * mean;
    float rs = rsqrtf(var + 1e-5f);
    int cc = g * 16 + tid;
    float av = gnw[cc] * rs;
    a[b * 512 + cc]  = av;
    cv[b * 512 + cc] = gnb[cc] - mean * av;
    sx[b * 512 + cc] = chS[tid];
  }
}

// swizzled LDS chunk for ds_read (BK=64 kernels): chunk c of row r at c^(r&7)
#define SWZ_RD(row16, chunk) ((((chunk) ^ ((row16) & 7)) << 3))

// ---------------------------------------------------------------------------
// Kernel 2 (combo): range-partitioned concurrent jobs. 32 KB static LDS
// (BK=32 gram) -> 5 blocks/CU so the transpose/wconv flood runs wide.
//   bid [0,640)      : split-K symmetric Gram partials (BK=32, R12-verified)
//   bid [640,8832)   : xb -> xT tiled transpose
//   bid [8832,8912)  : per-batch GEMVs (eq,uq,ek,uk,hv)
//   bid [8912,9936)  : Wq->bf16, WpI=bf16(I+Wp)
// ---------------------------------------------------------------------------
__global__ __launch_bounds__(256) void k_combo(const u16* __restrict__ xb,
    float* __restrict__ part, u16* __restrict__ xT,
    const float* __restrict__ wq, const float* __restrict__ bq,
    const float* __restrict__ wk, const float* __restrict__ bk,
    const float* __restrict__ wv, const float* __restrict__ bv,
    const float* __restrict__ wp,
    const float* __restrict__ a, const float* __restrict__ cv,
    const float* __restrict__ sx,
    u16* __restrict__ wqb, u16* __restrict__ wpI,
    float* __restrict__ eq, float* __restrict__ uq, float* __restrict__ ek,
    float* __restrict__ uk, float* __restrict__ hv)
{
  __shared__ u16 As[2][128 * 32];
  __shared__ u16 Bs[2][128 * 32];
  const int bid = blockIdx.x;
  const int tid = threadIdx.x;

  if (bid >= 8912) {                      // ---- wconv ----
    int i = (bid - 8912) * 256 + tid;
    wqb[i] = f2bf(wq[i]);
    float add = ((i >> 9) == (i & 511)) ? 1.f : 0.f;
    wpI[i] = f2bf(wp[i] + add);
    return;
  }

  if (bid >= 8832) {                      // ---- k_vec ----
    int v = bid - 8832;
    int b = v / 5, which = v % 5;
    float* vec = (float*)&As[0][0];
    for (int i = tid; i < 512; i += 256)
      vec[i] = (which == 1 || which == 3) ? a[b * 512 + i] * sx[b * 512 + i]
                                          : cv[b * 512 + i];
    __syncthreads();
    const float* W = (which < 2) ? wq : (which < 4) ? wk : wv;
    const float* bias = (which == 0) ? bq : (which == 2) ? bk
                      : (which == 4) ? bv : nullptr;
    float* outp = (which == 0) ? eq : (which == 1) ? uq : (which == 2) ? ek
                : (which == 3) ? uk : hv;
    for (int c = tid; c < 512; c += 256) {
      const float* wr = W + (long)c * 512;
      float s2 = 0.f;
      for (int e = 0; e < 512; e += 4) {
        float4 w4 = *(const float4*)(wr + e);
        s2 += w4.x * vec[e] + w4.y * vec[e+1] + w4.z * vec[e+2] + w4.w * vec[e+3];
      }
      if (bias) s2 += bias[c];
      outp[b * 512 + c] = s2;
    }
    return;
  }

  if (bid >= 640) {                       // ---- transpose ----
    int t = bid - 640;
    int i0 = (t & 63) * 64, e0 = ((t >> 6) & 7) * 64, b = t >> 9;
    u16 (*tl)[72] = (u16(*)[72])(&As[0][0]);   // 9.2 KB < 16 KB (As)
    #pragma unroll
    for (int p = 0; p < 2; ++p) {
      int task = p * 256 + tid;
      int er = task >> 3, ic = (task & 7) * 8;
      us8 v = *(const us8*)(xb + ((long)(b * 512 + e0 + er)) * 4096 + i0 + ic);
      #pragma unroll
      for (int j = 0; j < 8; ++j) tl[ic + j][er] = v[j];
    }
    __syncthreads();
    #pragma unroll
    for (int p = 0; p < 2; ++p) {
      int task = p * 256 + tid;
      int ir = task >> 3, ec = (task & 7) * 8;
      us8 w = *(const us8*)&tl[ir][ec];
      *(us8*)(xT + ((long)(b * 4096 + i0 + ir)) * 512 + e0 + ec) = w;
    }
    return;
  }

  // ---- gram_split (BK=32, counted-vmcnt 2-phase + 4-chunk swizzle) ----
  const int wave = tid >> 6, lane = tid & 63;
  const int tile = bid % 10, split = (bid / 10) & 3;
  const int b = bid / 40;
  const int tm = d_rt[tile] * 128, tn = d_ct[tile] * 128;
  const u16* Xb = xb + (long)b * 512 * 4096;
  const int wm = (wave >> 1) << 6, wn = (wave & 1) << 6;
  const int l15 = lane & 15, l4 = lane >> 4;

  f32x4 acc[4][4];
  f32x4 z = {0.f, 0.f, 0.f, 0.f};
  #pragma unroll
  for (int fm = 0; fm < 4; ++fm)
    #pragma unroll
    for (int fn = 0; fn < 4; ++fn) acc[fm][fn] = z;

  const int k0 = split * 1024;
  const int NT = 32;   // 32 steps of BK=32

  auto STAGE = [&](int buf, int kt) {
    #pragma unroll
    for (int l = 0; l < 2; ++l) {
      int fbase = l * 256 + wave * 64;       // wave-uniform LDS base (x8 elems)
      int flat  = fbase + lane;
      int row = flat >> 2, cseg = flat & 3;
      int gcol = kt + ((cseg ^ (row & 3)) << 3);
      ASYNC_CP16(Xb + (long)(tm + row) * 4096 + gcol, &As[buf][fbase * 8]);
      ASYNC_CP16(Xb + (long)(tn + row) * 4096 + gcol, &Bs[buf][fbase * 8]);
    }
  };

  STAGE(0, k0);
  int cur = 0;
  const int rswz = (l4 ^ (l15 & 3)) << 3;   // read-side swizzle (row&3 == l15&3)
  for (int t = 0; t < NT; ++t) {
    if (t + 1 < NT) {
      STAGE(cur ^ 1, k0 + (t + 1) * 32);
      asm volatile("s_waitcnt vmcnt(4)" ::: "memory");
    } else {
      asm volatile("s_waitcnt vmcnt(0)" ::: "memory");
    }
    __builtin_amdgcn_s_barrier();
    __builtin_amdgcn_sched_barrier(0);
    bf16x8 af[4], bfr[4];
    #pragma unroll
    for (int f = 0; f < 4; ++f) {
      af[f]  = *(const bf16x8*)&As[cur][(wm + f * 16 + l15) * 32 + rswz];
      bfr[f] = *(const bf16x8*)&Bs[cur][(wn + f * 16 + l15) * 32 + rswz];
    }
    #pragma unroll
    for (int fm = 0; fm < 4; ++fm)
      #pragma unroll
      for (int fn = 0; fn < 4; ++fn)
        acc[fm][fn] = __builtin_amdgcn_mfma_f32_16x16x32_bf16(
            bfr[fn], af[fm], acc[fm][fn], 0, 0, 0);
    __builtin_amdgcn_sched_barrier(0);
    __builtin_amdgcn_s_barrier();
    cur ^= 1;
  }

  float* pp = part + ((((long)split * 16 + b) * 10 + tile) << 14);
  #pragma unroll
  for (int fm = 0; fm < 4; ++fm) {
    const int row = wm + fm * 16 + l15;
    #pragma unroll
    for (int fn = 0; fn < 4; ++fn) {
      const int col = wn + fn * 16 + l4 * 4;
      *(f32x4*)&pp[row * 128 + col] = acc[fm][fn];
    }
  }
}

// ---------------------------------------------------------------------------
// Kernel 4b: reduce 4 splits, scale, write Gp (+mirror via LDS).
// ---------------------------------------------------------------------------
__global__ __launch_bounds__(512) void k_gram_reduce(
    const float* __restrict__ part, const float* __restrict__ a,
    u16* __restrict__ Gp)
{
  const int tile = blockIdx.x, b = blockIdx.y;
  const int tmt = d_rt[tile], tnt = d_ct[tile];
  const int tm = tmt * 128, tn = tnt * 128;
  const int tid = threadIdx.x;
  __shared__ u16 t[128][130];
  const float* p0 = part + (((long)b * 10 + tile) << 14);
  const long ss = (long)16 * 10 * 16384;
  u16* Gb = Gp + (long)b * 262144;
  const float acol = a[b * 512 + tn + (tid & 127)];
  for (int chunk = 0; chunk < 32; ++chunk) {
    int idx = chunk * 512 + tid;
    int row = idx >> 7, col = idx & 127;
    float v = p0[idx] + p0[idx + ss] + p0[idx + 2 * ss] + p0[idx + 3 * ss];
    v *= a[b * 512 + tm + row] * acol;
    u16 bf = f2bf(v);
    Gb[(tm + row) * 512 + tn + col] = bf;
    t[row][col] = bf;
  }
  if (tmt != tnt) {
    __syncthreads();
    for (int chunk = 0; chunk < 32; ++chunk) {
      int idx = chunk * 512 + tid;
      int row = idx >> 7, col = idx & 127;
      Gb[(tn + row) * 512 + tm + col] = t[col][row];
    }
  }
}

// ---------------------------------------------------------------------------
// Kernel 4m: 64^2 batched NT-GEMM (mid GEMMs), counted-vmcnt + swizzle.
// EPI 1: P  -> fp32 out plain (float4)
// EPI 2: W3 -> zero init, out bf16 v*a[col] (ushort4)   [A carries I+Wp]
// ---------------------------------------------------------------------------
template<int EPI>
__global__ __launch_bounds__(256) void k_ntgemm64(
    const u16* __restrict__ A, long sA, int lda,
    const u16* __restrict__ B, long sB, int ldb,
    float* __restrict__ fout, long sF, int ldf,
    u16* __restrict__ bout, long sO, int ldo_,
    const float* __restrict__ ascale)
{
  __shared__ u16 As[2][64 * 64];
  __shared__ u16 Bs[2][64 * 64];
  const int tid = threadIdx.x;
  const int wave = tid >> 6, lane = tid & 63;
  const int b = blockIdx.y;
  const int tm = (blockIdx.x >> 3) * 64, tn = (blockIdx.x & 7) * 64;
  const u16* Ab = A + sA * b;
  const u16* Bb = B + sB * b;
  const int wm = (wave >> 1) << 5, wn = (wave & 1) << 5;
  const int l15 = lane & 15, l4 = lane >> 4;

  f32x4 acc[2][2];
  f32x4 z = {0.f, 0.f, 0.f, 0.f};
  #pragma unroll
  for (int fm = 0; fm < 2; ++fm)
    #pragma unroll
    for (int fn = 0; fn < 2; ++fn) acc[fm][fn] = z;

  const int qa = wave * 2;
  const int srow = lane >> 3;
  const int NT = 8;   // K = 512

  auto STAGE = [&](int buf, int kt) {
    #pragma unroll
    for (int j = 0; j < 2; ++j) {
      int q = qa + j;
      int row = q * 8 + srow;
      int gcol = kt + (((lane & 7) ^ (row & 7)) << 3);
      ASYNC_CP16(Ab + (long)(tm + row) * lda + gcol, &As[buf][q * 512]);
      ASYNC_CP16(Bb + (long)(tn + row) * ldb + gcol, &Bs[buf][q * 512]);
    }
  };

  STAGE(0, 0);
  int cur = 0;
  for (int t = 0; t < NT; ++t) {
    if (t + 1 < NT) {
      STAGE(cur ^ 1, (t + 1) * 64);
      asm volatile("s_waitcnt vmcnt(4)" ::: "memory");
    } else {
      asm volatile("s_waitcnt vmcnt(0)" ::: "memory");
    }
    __builtin_amdgcn_s_barrier();
    __builtin_amdgcn_sched_barrier(0);
    #pragma unroll
    for (int kk = 0; kk < 2; ++kk) {
      bf16x8 af[2], bfr[2];
      #pragma unroll
      for (int f = 0; f < 2; ++f) {
        af[f]  = *(const bf16x8*)&As[cur][(wm + f * 16 + l15) * 64 +
                                          SWZ_RD(l15, l4 + kk * 4)];
        bfr[f] = *(const bf16x8*)&Bs[cur][(wn + f * 16 + l15) * 64 +
                                          SWZ_RD(l15, l4 + kk * 4)];
      }
      #pragma unroll
      for (int fm = 0; fm < 2; ++fm)
        #pragma unroll
        for (int fn = 0; fn < 2; ++fn)
          acc[fm][fn] = __builtin_amdgcn_mfma_f32_16x16x32_bf16(
              bfr[fn], af[fm], acc[fm][fn], 0, 0, 0);
    }
    __builtin_amdgcn_sched_barrier(0);
    __builtin_amdgcn_s_barrier();
    cur ^= 1;
  }

  #pragma unroll
  for (int fm = 0; fm < 2; ++fm) {
    const int row = tm + wm + fm * 16 + l15;
    #pragma unroll
    for (int fn = 0; fn < 2; ++fn) {
      const int col = tn + wn + fn * 16 + l4 * 4;
      f32x4 v = acc[fm][fn];
      if (EPI == 1) {
        *(f32x4*)&fout[sF * b + (long)row * ldf + col] = v;
      } else {
        f32x4 sc = *(const f32x4*)&ascale[b * 512 + col];
        ushort4 o;
        o.x = f2bf(v[0] * sc[0]); o.y = f2bf(v[1] * sc[1]);
        o.z = f2bf(v[2] * sc[2]); o.w = f2bf(v[3] * sc[3]);
        *(ushort4*)&bout[sO * b + (long)row * ldo_ + col] = o;
      }
    }
  }
}

// ---------------------------------------------------------------------------
// Kernel 4c: final GEMM out = W3 @ x + c3. 256x256 tile, 8 waves, counted
// vmcnt + swizzle. bx remap pairs m-blocks per XCD.
// ---------------------------------------------------------------------------
__global__ __launch_bounds__(512, 2) void k_final(
    const u16* __restrict__ W3, const u16* __restrict__ xT,
    const float* __restrict__ cadd, float* __restrict__ out)
{
  __shared__ u16 As[2][256 * 64];
  __shared__ u16 Bs[2][256 * 64];
  const int tid = threadIdx.x;
  const int wave = tid >> 6, lane = tid & 63;
  const int b = blockIdx.y;
  const int bxx = blockIdx.x;
  const int mi = (bxx >> 3) & 1;
  const int ni = (bxx & 7) | ((bxx >> 4) << 3);
  const int tm = mi * 256, tn = ni * 256;
  const u16* Ab = W3 + (long)b * 262144;
  const u16* Bb = xT + (long)b * 4096 * 512;
  const int wmA = (wave >> 2) * 128, wnB = (wave & 3) * 64;
  const int l15 = lane & 15, l4 = lane >> 4;

  f32x4 acc[8][4];
  f32x4 z = {0.f, 0.f, 0.f, 0.f};
  #pragma unroll
  for (int fm = 0; fm < 8; ++fm)
    #pragma unroll
    for (int fn = 0; fn < 4; ++fn) acc[fm][fn] = z;

  const int qa = wave * 4;
  const int srow = lane >> 3;
  const int NT = 8;   // K = 512

  auto STAGE = [&](int buf, int kt) {
    #pragma unroll
    for (int j = 0; j < 4; ++j) {
      int q = qa + j;
      int row = q * 8 + srow;
      int gcol = kt + (((lane & 7) ^ (row & 7)) << 3);
      ASYNC_CP16(Ab + (long)(tm + row) * 512 + gcol, &As[buf][q * 512]);
      ASYNC_CP16(Bb + (long)(tn + row) * 512 + gcol, &Bs[buf][q * 512]);
    }
  };

  STAGE(0, 0);
  int cur = 0;
  for (int t = 0; t < NT; ++t) {
    if (t + 1 < NT) {
      STAGE(cur ^ 1, (t + 1) * 64);
      asm volatile("s_waitcnt vmcnt(8)" ::: "memory");
    } else {
      asm volatile("s_waitcnt vmcnt(0)" ::: "memory");
    }
    __builtin_amdgcn_s_barrier();
    __builtin_amdgcn_sched_barrier(0);
    #pragma unroll
    for (int kk = 0; kk < 2; ++kk) {
      bf16x8 af[8], bfr[4];
      #pragma unroll
      for (int f = 0; f < 8; ++f)
        af[f]  = *(const bf16x8*)&As[cur][(wmA + f * 16 + l15) * 64 +
                                          SWZ_RD(l15, l4 + kk * 4)];
      #pragma unroll
      for (int f = 0; f < 4; ++f)
        bfr[f] = *(const bf16x8*)&Bs[cur][(wnB + f * 16 + l15) * 64 +
                                          SWZ_RD(l15, l4 + kk * 4)];
      #pragma unroll
      for (int fm = 0; fm < 8; ++fm)
        #pragma unroll
        for (int fn = 0; fn < 4; ++fn)
          acc[fm][fn] = __builtin_amdgcn_mfma_f32_16x16x32_bf16(
              bfr[fn], af[fm], acc[fm][fn], 0, 0, 0);
    }
    __builtin_amdgcn_sched_barrier(0);
    __builtin_amdgcn_s_barrier();
    cur ^= 1;
  }

  float* ob = out + (long)b * 512 * 4096;
  #pragma unroll
  for (int fm = 0; fm < 8; ++fm) {
    const int row = tm + wmA + fm * 16 + l15;
    const float ca = cadd[b * 512 + row];
    #pragma unroll
    for (int fn = 0; fn < 4; ++fn) {
      const int col = tn + wnB + fn * 16 + l4 * 4;
      f32x4 v = acc[fm][fn];
      v[0] += ca; v[1] += ca; v[2] += ca; v[3] += ca;
      *(f32x4*)&ob[(long)row * 4096 + col] = v;
    }
  }
}

// ---------------------------------------------------------------------------
// Kernel 6: per-(b,g) scores + softmax + UT = (A_bd*Wv)^T (bf16), oc=A_bd*hv.
// ---------------------------------------------------------------------------
__global__ __launch_bounds__(256) void k_scores(
    const float* __restrict__ P,
    const float* __restrict__ wk, const float* __restrict__ wv,
    const float* __restrict__ eq, const float* __restrict__ uq,
    const float* __restrict__ ek, const float* __restrict__ uk,
    const float* __restrict__ hv,
    u16* __restrict__ UT, float* __restrict__ oc)
{
  int b = blockIdx.x >> 5, g = blockIdx.x & 31;
  int tid = threadIdx.x;
  __shared__ float Pl[16 * 516];
  __shared__ float Wl[16 * 516];
  __shared__ float at[16][16];

  const float* Pb = P + (long)b * 262144 + g * 16 * 512;
  for (int t = tid; t < 16 * 128; t += 256) {
    int r = t >> 7, q = t & 127;
    *(float4*)&Pl[r * 516 + q * 4] = *(const float4*)(Pb + r * 512 + q * 4);
  }
  const float* Wkb = wk + (long)g * 16 * 512;
  for (int t = tid; t < 16 * 128; t += 256) {
    int r = t >> 7, q = t & 127;
    *(float4*)&Wl[r * 516 + q * 4] = *(const float4*)(Wkb + r * 512 + q * 4);
  }
  __syncthreads();

  int c = tid >> 4, d = tid & 15;
  float s0 = 0.f;
  for (int e = 0; e < 512; e += 4) {
    float4 p4 = *(const float4*)&Pl[c * 516 + e];
    float4 w4 = *(const float4*)&Wl[d * 516 + e];
    s0 += p4.x * w4.x + p4.y * w4.y + p4.z * w4.z + p4.w * w4.w;
  }
  float eqc = eq[b * 512 + g * 16 + c], uqc = uq[b * 512 + g * 16 + c];
  float ekd = ek[b * 512 + g * 16 + d], ukd = uk[b * 512 + g * 16 + d];
  float s = (s0 + eqc * ukd + uqc * ekd + 4096.f * eqc * ekd) * 0.04419417382415922f;
  float m = s;
  for (int off = 8; off; off >>= 1) m = fmaxf(m, __shfl_xor(m, off));
  float p = expf(s - m);
  float sum = p;
  for (int off = 8; off; off >>= 1) sum += __shfl_xor(sum, off);
  at[c][d] = p / sum;
  __syncthreads();

  const float* Wvb = wv + (long)g * 16 * 512;
  for (int t = tid; t < 16 * 128; t += 256) {
    int r = t >> 7, q = t & 127;
    *(float4*)&Wl[r * 516 + q * 4] = *(const float4*)(Wvb + r * 512 + q * 4);
  }
  __syncthreads();

  for (int t = 0; t < 32; ++t) {
    int flat = t * 256 + tid;
    int cc = flat >> 9, e = flat & 511;
    float a2 = 0.f;
    #pragma unroll
    for (int dd = 0; dd < 16; ++dd) a2 += at[cc][dd] * Wl[dd * 516 + e];
    Pl[cc * 516 + e] = a2;
  }
  if (tid < 16) {
    float o2 = 0.f;
    #pragma unroll
    for (int dd = 0; dd < 16; ++dd) o2 += at[tid][dd] * hv[b * 512 + g * 16 + dd];
    oc[b * 512 + g * 16 + tid] = o2;
  }
  __syncthreads();
  for (int t = 0; t < 32; ++t) {
    int flat = t * 256 + tid;
    int cc = flat & 15, e = flat >> 4;
    UT[(long)b * 262144 + e * 512 + g * 16 + cc] = f2bf(Pl[cc * 516 + e]);
  }
}

// ---------------------------------------------------------------------------
// Kernel 7: c3 = (I+Wp)*oc + bp.
// ---------------------------------------------------------------------------
__global__ __launch_bounds__(256) void k_c3(const float* __restrict__ wp,
    const float* __restrict__ bp, const float* __restrict__ oc,
    float* __restrict__ c3)
{
  int b = blockIdx.x >> 1;
  int o = (blockIdx.x & 1) * 256 + threadIdx.x;
  __shared__ float ov[512];
  for (int i = threadIdx.x; i < 512; i += 256) ov[i] = oc[b * 512 + i];
  __syncthreads();
  const float* wr = wp + (long)o * 512;
  float s = 0.f;
  for (int e = 0; e < 512; e += 4) {
    float4 w4 = *(const float4*)(wr + e);
    s += w4.x * ov[e] + w4.y * ov[e + 1] + w4.z * ov[e + 2] + w4.w * ov[e + 3];
  }
  c3[b * 512 + o] = oc[b * 512 + o] + s + bp[o];
}

// ---------------------------------------------------------------------------
extern "C" void kernel_launch(void* const* d_in, const int* in_sizes, int n_in,
                              void* d_out, int out_size, void* d_ws, size_t ws_size,
                              hipStream_t stream)
{
  (void)in_sizes; (void)n_in; (void)out_size; (void)ws_size;
  const float* x   = (const float*)d_in[0];
  const float* gnw = (const float*)d_in[1];
  const float* gnb = (const float*)d_in[2];
  const float* wq  = (const float*)d_in[3];
  const float* bq  = (const float*)d_in[4];
  const float* wk  = (const float*)d_in[5];
  const float* bk  = (const float*)d_in[6];
  const float* wv  = (const float*)d_in[7];
  const float* bv  = (const float*)d_in[8];
  const float* wp  = (const float*)d_in[9];
  const float* bp  = (const float*)d_in[10];
  float* out = (float*)d_out;

  char* ws = (char*)d_ws;
  u16* xT  = (u16*)ws;  ws += (size_t)16 * 4096 * 512 * 2;  // 64 MB
  u16* Gp  = (u16*)ws;  ws += (size_t)16 * 512 * 512 * 2;   // 8 MB
  float* P = (float*)ws; ws += (size_t)16 * 512 * 512 * 4;  // 16 MB
  u16* UT  = (u16*)ws;  ws += (size_t)16 * 512 * 512 * 2;   // 8 MB
  u16* W3  = (u16*)ws;  ws += (size_t)16 * 512 * 512 * 2;   // 8 MB
  u16* wqb = (u16*)ws;  ws += (size_t)512 * 512 * 2;
  u16* wpI = (u16*)ws;  ws += (size_t)512 * 512 * 2;
  float* a  = (float*)ws; ws += 16 * 512 * 4;
  float* cv = (float*)ws; ws += 16 * 512 * 4;
  float* sx = (float*)ws; ws += 16 * 512 * 4;
  float* eq = (float*)ws; ws += 16 * 512 * 4;
  float* uq = (float*)ws; ws += 16 * 512 * 4;
  float* ek = (float*)ws; ws += 16 * 512 * 4;
  float* uk = (float*)ws; ws += 16 * 512 * 4;
  float* hv = (float*)ws; ws += 16 * 512 * 4;
  float* oc = (float*)ws; ws += 16 * 512 * 4;
  float* c3 = (float*)ws; ws += 16 * 512 * 4;

  u16* xb = (u16*)d_out;                            // d_out[0..64MB): x_bf16
  float* part = (float*)((char*)d_out + 67108864);  // d_out[64..104MB): partials

  k_stats<<<512, 256, 0, stream>>>(x, gnw, gnb, xb, a, cv, sx);
  // combo: gram_split(640, BK=32) + transpose(8192) + vec(80) + wconv(1024)
  k_combo<<<9936, 256, 0, stream>>>(xb, part, xT,
                                    wq, bq, wk, bk, wv, bv, wp,
                                    a, cv, sx, wqb, wpI,
                                    eq, uq, ek, uk, hv);
  k_gram_reduce<<<dim3(10, 16), 512, 0, stream>>>(part, a, Gp);
  // P = Wq @ G'  (fp32 out; uses G' symmetry for NT layout)
  k_ntgemm64<1><<<dim3(64, 16), 256, 0, stream>>>(
      wqb, 0, 512, Gp, 262144, 512,
      P, 262144, 512, nullptr, 0, 0, nullptr);
  k_scores<<<512, 256, 0, stream>>>(P, wk, wv, eq, uq, ek, uk, hv, UT, oc);
  k_c3<<<32, 256, 0, stream>>>(wp, bp, oc, c3);
  // W3 = (I+Wp) @ U * D_a  (bf16; A = wpI, B = UT)
  k_ntgemm64<2><<<dim3(64, 16), 256, 0, stream>>>(
      wpI, 0, 512, UT, 262144, 512,
      nullptr, 0, 0, W3, 262144, 512, a);
  // out = W3 @ x + c3  (256^2 tile)
  k_final<<<dim3(32, 16), 512, 0, stream>>>(W3, xT, c3, out);
}

// Round 16
// 247.670 us; speedup vs baseline: 1.1791x; 1.1791x over previous
//
#include <hip/hip_runtime.h>

typedef __attribute__((ext_vector_type(8))) short bf16x8;
typedef __attribute__((ext_vector_type(4))) float f32x4;
typedef __attribute__((ext_vector_type(8))) unsigned short us8;
typedef unsigned short u16;
typedef unsigned int u32;

__device__ __forceinline__ u16 f2bf(float f){
  u32 u = __builtin_bit_cast(u32, f);
  u32 r = (u + 0x7fffu + ((u >> 16) & 1u)) >> 16;
  return (u16)r;
}

#define ASYNC_CP16(gp, lp) __builtin_amdgcn_global_load_lds( \
    (__attribute__((address_space(1))) void*)(gp), \
    (__attribute__((address_space(3))) void*)(lp), 16, 0, 0)

// upper-triangular 128x128 tile table for the symmetric Gram (4x4 tiles)
__device__ const int d_rt[10] = {0,0,0,0,1,1,1,2,2,3};
__device__ const int d_ct[10] = {0,1,2,3,1,2,3,2,3,3};

// ---------------------------------------------------------------------------
// Kernel 1: GroupNorm stats + x -> bf16 conversion.
// ---------------------------------------------------------------------------
__global__ __launch_bounds__(256) void k_stats(const float* __restrict__ x,
    const float* __restrict__ gnw, const float* __restrict__ gnb,
    u16* __restrict__ xb, float* __restrict__ a, float* __restrict__ cv,
    float* __restrict__ sx)
{
  int b = blockIdx.x >> 5;
  int g = blockIdx.x & 31;
  int tid = threadIdx.x;
  int cl = tid >> 4;
  int l16 = tid & 15;
  int c = g * 16 + cl;
  const float* xp = x + ((long)(b * 512 + c)) * 4096;
  u16* xbp = xb + ((long)(b * 512 + c)) * 4096;
  float s = 0.f, sq = 0.f;
  for (int it = 0; it < 64; ++it) {
    int i4 = it * 16 + l16;
    float4 v = *(const float4*)(xp + i4 * 4);
    s  += v.x + v.y + v.z + v.w;
    sq += v.x * v.x + v.y * v.y + v.z * v.z + v.w * v.w;
    ushort4 o;
    o.x = f2bf(v.x); o.y = f2bf(v.y); o.z = f2bf(v.z); o.w = f2bf(v.w);
    *(ushort4*)(xbp + i4 * 4) = o;
  }
  for (int off = 8; off; off >>= 1) { s += __shfl_xor(s, off); sq += __shfl_xor(sq, off); }
  __shared__ float chS[16], chQ[16];
  if (l16 == 0) { chS[cl] = s; chQ[cl] = sq; }
  __syncthreads();
  if (tid < 16) {
    float S = 0.f, Q = 0.f;
    for (int j = 0; j < 16; ++j) { S += chS[j]; Q += chQ[j]; }
    float mean = S * (1.f / 65536.f);
    float var  = Q * (1.f / 65536.f) - mean * mean;
    float rs = rsqrtf(var + 1e-5f);
    int cc = g * 16 + tid;
    float av = gnw[cc] * rs;
    a[b * 512 + cc]  = av;
    cv[b * 512 + cc] = gnb[cc] - mean * av;
    sx[b * 512 + cc] = chS[tid];
  }
}

// swizzled LDS chunk for ds_read: global chunk c of row r lives at c^(r&7)
#define SWZ_RD(row16, chunk) ((((chunk) ^ ((row16) & 7)) << 3))

// ---------------------------------------------------------------------------
// Kernel 2 (combo): range-partitioned concurrent jobs, TRANSPOSE-FIRST order
// (convoy fix: BW flood fills all CUs at full width before the long gram
// blocks occupy the LDS slots).
//   bid [0,8192)     : xb -> xT tiled transpose
//   bid [8192,8272)  : per-batch GEMVs (eq,uq,ek,uk,hv)
//   bid [8272,9296)  : Wq->bf16, WpI=bf16(I+Wp)
//   bid [9296,9936)  : split-K symmetric Gram partials (BK=64, R14-proven)
// ---------------------------------------------------------------------------
__global__ __launch_bounds__(256) void k_combo(const u16* __restrict__ xb,
    float* __restrict__ part, u16* __restrict__ xT,
    const float* __restrict__ wq, const float* __restrict__ bq,
    const float* __restrict__ wk, const float* __restrict__ bk,
    const float* __restrict__ wv, const float* __restrict__ bv,
    const float* __restrict__ wp,
    const float* __restrict__ a, const float* __restrict__ cv,
    const float* __restrict__ sx,
    u16* __restrict__ wqb, u16* __restrict__ wpI,
    float* __restrict__ eq, float* __restrict__ uq, float* __restrict__ ek,
    float* __restrict__ uk, float* __restrict__ hv)
{
  __shared__ u16 As[2][128 * 64];
  __shared__ u16 Bs[2][128 * 64];
  const int bid = blockIdx.x;
  const int tid = threadIdx.x;

  if (bid < 8192) {                       // ---- transpose ----
    int t = bid;
    int i0 = (t & 63) * 64, e0 = ((t >> 6) & 7) * 64, b = t >> 9;
    u16 (*tl)[72] = (u16(*)[72])(&As[0][0]);
    #pragma unroll
    for (int p = 0; p < 2; ++p) {
      int task = p * 256 + tid;
      int er = task >> 3, ic = (task & 7) * 8;
      us8 v = *(const us8*)(xb + ((long)(b * 512 + e0 + er)) * 4096 + i0 + ic);
      #pragma unroll
      for (int j = 0; j < 8; ++j) tl[ic + j][er] = v[j];
    }
    __syncthreads();
    #pragma unroll
    for (int p = 0; p < 2; ++p) {
      int task = p * 256 + tid;
      int ir = task >> 3, ec = (task & 7) * 8;
      us8 w = *(const us8*)&tl[ir][ec];
      *(us8*)(xT + ((long)(b * 4096 + i0 + ir)) * 512 + e0 + ec) = w;
    }
    return;
  }

  if (bid < 8272) {                       // ---- k_vec ----
    int v = bid - 8192;
    int b = v / 5, which = v % 5;
    float* vec = (float*)&As[0][0];
    for (int i = tid; i < 512; i += 256)
      vec[i] = (which == 1 || which == 3) ? a[b * 512 + i] * sx[b * 512 + i]
                                          : cv[b * 512 + i];
    __syncthreads();
    const float* W = (which < 2) ? wq : (which < 4) ? wk : wv;
    const float* bias = (which == 0) ? bq : (which == 2) ? bk
                      : (which == 4) ? bv : nullptr;
    float* outp = (which == 0) ? eq : (which == 1) ? uq : (which == 2) ? ek
                : (which == 3) ? uk : hv;
    for (int c = tid; c < 512; c += 256) {
      const float* wr = W + (long)c * 512;
      float s2 = 0.f;
      for (int e = 0; e < 512; e += 4) {
        float4 w4 = *(const float4*)(wr + e);
        s2 += w4.x * vec[e] + w4.y * vec[e+1] + w4.z * vec[e+2] + w4.w * vec[e+3];
      }
      if (bias) s2 += bias[c];
      outp[b * 512 + c] = s2;
    }
    return;
  }

  if (bid < 9296) {                       // ---- wconv ----
    int i = (bid - 8272) * 256 + tid;
    wqb[i] = f2bf(wq[i]);
    float add = ((i >> 9) == (i & 511)) ? 1.f : 0.f;
    wpI[i] = f2bf(wp[i] + add);
    return;
  }

  // ---- gram_split (BK=64, counted-vmcnt 2-phase + swizzle) ----
  const int gidx = bid - 9296;            // 0..639
  const int wave = tid >> 6, lane = tid & 63;
  const int tile = gidx % 10, split = (gidx / 10) & 3;
  const int b = gidx / 40;
  const int tm = d_rt[tile] * 128, tn = d_ct[tile] * 128;
  const u16* Xb = xb + (long)b * 512 * 4096;
  const int wm = (wave >> 1) << 6, wn = (wave & 1) << 6;
  const int l15 = lane & 15, l4 = lane >> 4;

  f32x4 acc[4][4];
  f32x4 z = {0.f, 0.f, 0.f, 0.f};
  #pragma unroll
  for (int fm = 0; fm < 4; ++fm)
    #pragma unroll
    for (int fn = 0; fn < 4; ++fn) acc[fm][fn] = z;

  const int qa = wave * 4;
  const int srow = lane >> 3;
  const int k0 = split * 1024;
  const int NT = 16;

  auto STAGE = [&](int buf, int kt) {
    #pragma unroll
    for (int j = 0; j < 4; ++j) {
      int q = qa + j;
      int row = q * 8 + srow;
      int gcol = kt + (((lane & 7) ^ (row & 7)) << 3);
      ASYNC_CP16(Xb + (long)(tm + row) * 4096 + gcol, &As[buf][q * 512]);
      ASYNC_CP16(Xb + (long)(tn + row) * 4096 + gcol, &Bs[buf][q * 512]);
    }
  };

  STAGE(0, k0);
  int cur = 0;
  for (int t = 0; t < NT; ++t) {
    if (t + 1 < NT) {
      STAGE(cur ^ 1, k0 + (t + 1) * 64);
      asm volatile("s_waitcnt vmcnt(8)" ::: "memory");
    } else {
      asm volatile("s_waitcnt vmcnt(0)" ::: "memory");
    }
    __builtin_amdgcn_s_barrier();
    __builtin_amdgcn_sched_barrier(0);
    #pragma unroll
    for (int kk = 0; kk < 2; ++kk) {
      bf16x8 af[4], bfr[4];
      #pragma unroll
      for (int f = 0; f < 4; ++f) {
        af[f]  = *(const bf16x8*)&As[cur][(wm + f * 16 + l15) * 64 +
                                          SWZ_RD(l15, l4 + kk * 4)];
        bfr[f] = *(const bf16x8*)&Bs[cur][(wn + f * 16 + l15) * 64 +
                                          SWZ_RD(l15, l4 + kk * 4)];
      }
      #pragma unroll
      for (int fm = 0; fm < 4; ++fm)
        #pragma unroll
        for (int fn = 0; fn < 4; ++fn)
          acc[fm][fn] = __builtin_amdgcn_mfma_f32_16x16x32_bf16(
              bfr[fn], af[fm], acc[fm][fn], 0, 0, 0);
    }
    __builtin_amdgcn_sched_barrier(0);
    __builtin_amdgcn_s_barrier();
    cur ^= 1;
  }

  float* pp = part + ((((long)split * 16 + b) * 10 + tile) << 14);
  #pragma unroll
  for (int fm = 0; fm < 4; ++fm) {
    const int row = wm + fm * 16 + l15;
    #pragma unroll
    for (int fn = 0; fn < 4; ++fn) {
      const int col = wn + fn * 16 + l4 * 4;
      *(f32x4*)&pp[row * 128 + col] = acc[fm][fn];
    }
  }
}

// ---------------------------------------------------------------------------
// Kernel 4b: reduce 4 splits, scale, write Gp (+mirror via LDS).
// ---------------------------------------------------------------------------
__global__ __launch_bounds__(512) void k_gram_reduce(
    const float* __restrict__ part, const float* __restrict__ a,
    u16* __restrict__ Gp)
{
  const int tile = blockIdx.x, b = blockIdx.y;
  const int tmt = d_rt[tile], tnt = d_ct[tile];
  const int tm = tmt * 128, tn = tnt * 128;
  const int tid = threadIdx.x;
  __shared__ u16 t[128][130];
  const float* p0 = part + (((long)b * 10 + tile) << 14);
  const long ss = (long)16 * 10 * 16384;
  u16* Gb = Gp + (long)b * 262144;
  const float acol = a[b * 512 + tn + (tid & 127)];
  for (int chunk = 0; chunk < 32; ++chunk) {
    int idx = chunk * 512 + tid;
    int row = idx >> 7, col = idx & 127;
    float v = p0[idx] + p0[idx + ss] + p0[idx + 2 * ss] + p0[idx + 3 * ss];
    v *= a[b * 512 + tm + row] * acol;
    u16 bf = f2bf(v);
    Gb[(tm + row) * 512 + tn + col] = bf;
    t[row][col] = bf;
  }
  if (tmt != tnt) {
    __syncthreads();
    for (int chunk = 0; chunk < 32; ++chunk) {
      int idx = chunk * 512 + tid;
      int row = idx >> 7, col = idx & 127;
      Gb[(tn + row) * 512 + tm + col] = t[col][row];
    }
  }
}

// ---------------------------------------------------------------------------
// Kernel 4m: 64^2 batched NT-GEMM (mid GEMMs), counted-vmcnt + swizzle.
// EPI 1: P  -> fp32 out plain (float4)
// EPI 2: W3 -> zero init, out bf16 v*a[col] (ushort4)   [A carries I+Wp]
// ---------------------------------------------------------------------------
template<int EPI>
__global__ __launch_bounds__(256) void k_ntgemm64(
    const u16* __restrict__ A, long sA, int lda,
    const u16* __restrict__ B, long sB, int ldb,
    float* __restrict__ fout, long sF, int ldf,
    u16* __restrict__ bout, long sO, int ldo_,
    const float* __restrict__ ascale)
{
  __shared__ u16 As[2][64 * 64];
  __shared__ u16 Bs[2][64 * 64];
  const int tid = threadIdx.x;
  const int wave = tid >> 6, lane = tid & 63;
  const int b = blockIdx.y;
  const int tm = (blockIdx.x >> 3) * 64, tn = (blockIdx.x & 7) * 64;
  const u16* Ab = A + sA * b;
  const u16* Bb = B + sB * b;
  const int wm = (wave >> 1) << 5, wn = (wave & 1) << 5;
  const int l15 = lane & 15, l4 = lane >> 4;

  f32x4 acc[2][2];
  f32x4 z = {0.f, 0.f, 0.f, 0.f};
  #pragma unroll
  for (int fm = 0; fm < 2; ++fm)
    #pragma unroll
    for (int fn = 0; fn < 2; ++fn) acc[fm][fn] = z;

  const int qa = wave * 2;
  const int srow = lane >> 3;
  const int NT = 8;   // K = 512

  auto STAGE = [&](int buf, int kt) {
    #pragma unroll
    for (int j = 0; j < 2; ++j) {
      int q = qa + j;
      int row = q * 8 + srow;
      int gcol = kt + (((lane & 7) ^ (row & 7)) << 3);
      ASYNC_CP16(Ab + (long)(tm + row) * lda + gcol, &As[buf][q * 512]);
      ASYNC_CP16(Bb + (long)(tn + row) * ldb + gcol, &Bs[buf][q * 512]);
    }
  };

  STAGE(0, 0);
  int cur = 0;
  for (int t = 0; t < NT; ++t) {
    if (t + 1 < NT) {
      STAGE(cur ^ 1, (t + 1) * 64);
      asm volatile("s_waitcnt vmcnt(4)" ::: "memory");
    } else {
      asm volatile("s_waitcnt vmcnt(0)" ::: "memory");
    }
    __builtin_amdgcn_s_barrier();
    __builtin_amdgcn_sched_barrier(0);
    #pragma unroll
    for (int kk = 0; kk < 2; ++kk) {
      bf16x8 af[2], bfr[2];
      #pragma unroll
      for (int f = 0; f < 2; ++f) {
        af[f]  = *(const bf16x8*)&As[cur][(wm + f * 16 + l15) * 64 +
                                          SWZ_RD(l15, l4 + kk * 4)];
        bfr[f] = *(const bf16x8*)&Bs[cur][(wn + f * 16 + l15) * 64 +
                                          SWZ_RD(l15, l4 + kk * 4)];
      }
      #pragma unroll
      for (int fm = 0; fm < 2; ++fm)
        #pragma unroll
        for (int fn = 0; fn < 2; ++fn)
          acc[fm][fn] = __builtin_amdgcn_mfma_f32_16x16x32_bf16(
              bfr[fn], af[fm], acc[fm][fn], 0, 0, 0);
    }
    __builtin_amdgcn_sched_barrier(0);
    __builtin_amdgcn_s_barrier();
    cur ^= 1;
  }

  #pragma unroll
  for (int fm = 0; fm < 2; ++fm) {
    const int row = tm + wm + fm * 16 + l15;
    #pragma unroll
    for (int fn = 0; fn < 2; ++fn) {
      const int col = tn + wn + fn * 16 + l4 * 4;
      f32x4 v = acc[fm][fn];
      if (EPI == 1) {
        *(f32x4*)&fout[sF * b + (long)row * ldf + col] = v;
      } else {
        f32x4 sc = *(const f32x4*)&ascale[b * 512 + col];
        ushort4 o;
        o.x = f2bf(v[0] * sc[0]); o.y = f2bf(v[1] * sc[1]);
        o.z = f2bf(v[2] * sc[2]); o.w = f2bf(v[3] * sc[3]);
        *(ushort4*)&bout[sO * b + (long)row * ldo_ + col] = o;
      }
    }
  }
}

// ---------------------------------------------------------------------------
// Kernel 4c: final GEMM out = W3 @ x + c3. 256x256 tile, 8 waves, counted
// vmcnt + swizzle. bx remap pairs m-blocks per XCD.
// ---------------------------------------------------------------------------
__global__ __launch_bounds__(512, 2) void k_final(
    const u16* __restrict__ W3, const u16* __restrict__ xT,
    const float* __restrict__ cadd, float* __restrict__ out)
{
  __shared__ u16 As[2][256 * 64];
  __shared__ u16 Bs[2][256 * 64];
  const int tid = threadIdx.x;
  const int wave = tid >> 6, lane = tid & 63;
  const int b = blockIdx.y;
  const int bxx = blockIdx.x;
  const int mi = (bxx >> 3) & 1;
  const int ni = (bxx & 7) | ((bxx >> 4) << 3);
  const int tm = mi * 256, tn = ni * 256;
  const u16* Ab = W3 + (long)b * 262144;
  const u16* Bb = xT + (long)b * 4096 * 512;
  const int wmA = (wave >> 2) * 128, wnB = (wave & 3) * 64;
  const int l15 = lane & 15, l4 = lane >> 4;

  f32x4 acc[8][4];
  f32x4 z = {0.f, 0.f, 0.f, 0.f};
  #pragma unroll
  for (int fm = 0; fm < 8; ++fm)
    #pragma unroll
    for (int fn = 0; fn < 4; ++fn) acc[fm][fn] = z;

  const int qa = wave * 4;
  const int srow = lane >> 3;
  const int NT = 8;   // K = 512

  auto STAGE = [&](int buf, int kt) {
    #pragma unroll
    for (int j = 0; j < 4; ++j) {
      int q = qa + j;
      int row = q * 8 + srow;
      int gcol = kt + (((lane & 7) ^ (row & 7)) << 3);
      ASYNC_CP16(Ab + (long)(tm + row) * 512 + gcol, &As[buf][q * 512]);
      ASYNC_CP16(Bb + (long)(tn + row) * 512 + gcol, &Bs[buf][q * 512]);
    }
  };

  STAGE(0, 0);
  int cur = 0;
  for (int t = 0; t < NT; ++t) {
    if (t + 1 < NT) {
      STAGE(cur ^ 1, (t + 1) * 64);
      asm volatile("s_waitcnt vmcnt(8)" ::: "memory");
    } else {
      asm volatile("s_waitcnt vmcnt(0)" ::: "memory");
    }
    __builtin_amdgcn_s_barrier();
    __builtin_amdgcn_sched_barrier(0);
    #pragma unroll
    for (int kk = 0; kk < 2; ++kk) {
      bf16x8 af[8], bfr[4];
      #pragma unroll
      for (int f = 0; f < 8; ++f)
        af[f]  = *(const bf16x8*)&As[cur][(wmA + f * 16 + l15) * 64 +
                                          SWZ_RD(l15, l4 + kk * 4)];
      #pragma unroll
      for (int f = 0; f < 4; ++f)
        bfr[f] = *(const bf16x8*)&Bs[cur][(wnB + f * 16 + l15) * 64 +
                                          SWZ_RD(l15, l4 + kk * 4)];
      #pragma unroll
      for (int fm = 0; fm < 8; ++fm)
        #pragma unroll
        for (int fn = 0; fn < 4; ++fn)
          acc[fm][fn] = __builtin_amdgcn_mfma_f32_16x16x32_bf16(
              bfr[fn], af[fm], acc[fm][fn], 0, 0, 0);
    }
    __builtin_amdgcn_sched_barrier(0);
    __builtin_amdgcn_s_barrier();
    cur ^= 1;
  }

  float* ob = out + (long)b * 512 * 4096;
  #pragma unroll
  for (int fm = 0; fm < 8; ++fm) {
    const int row = tm + wmA + fm * 16 + l15;
    const float ca = cadd[b * 512 + row];
    #pragma unroll
    for (int fn = 0; fn < 4; ++fn) {
      const int col = tn + wnB + fn * 16 + l4 * 4;
      f32x4 v = acc[fm][fn];
      v[0] += ca; v[1] += ca; v[2] += ca; v[3] += ca;
      *(f32x4*)&ob[(long)row * 4096 + col] = v;
    }
  }
}

// ---------------------------------------------------------------------------
// Kernel 6: per-(b,g) scores + softmax + UT = (A_bd*Wv)^T (bf16), oc=A_bd*hv.
// ---------------------------------------------------------------------------
__global__ __launch_bounds__(256) void k_scores(
    const float* __restrict__ P,
    const float* __restrict__ wk, const float* __restrict__ wv,
    const float* __restrict__ eq, const float* __restrict__ uq,
    const float* __restrict__ ek, const float* __restrict__ uk,
    const float* __restrict__ hv,
    u16* __restrict__ UT, float* __restrict__ oc)
{
  int b = blockIdx.x >> 5, g = blockIdx.x & 31;
  int tid = threadIdx.x;
  __shared__ float Pl[16 * 516];
  __shared__ float Wl[16 * 516];
  __shared__ float at[16][16];

  const float* Pb = P + (long)b * 262144 + g * 16 * 512;
  for (int t = tid; t < 16 * 128; t += 256) {
    int r = t >> 7, q = t & 127;
    *(float4*)&Pl[r * 516 + q * 4] = *(const float4*)(Pb + r * 512 + q * 4);
  }
  const float* Wkb = wk + (long)g * 16 * 512;
  for (int t = tid; t < 16 * 128; t += 256) {
    int r = t >> 7, q = t & 127;
    *(float4*)&Wl[r * 516 + q * 4] = *(const float4*)(Wkb + r * 512 + q * 4);
  }
  __syncthreads();

  int c = tid >> 4, d = tid & 15;
  float s0 = 0.f;
  for (int e = 0; e < 512; e += 4) {
    float4 p4 = *(const float4*)&Pl[c * 516 + e];
    float4 w4 = *(const float4*)&Wl[d * 516 + e];
    s0 += p4.x * w4.x + p4.y * w4.y + p4.z * w4.z + p4.w * w4.w;
  }
  float eqc = eq[b * 512 + g * 16 + c], uqc = uq[b * 512 + g * 16 + c];
  float ekd = ek[b * 512 + g * 16 + d], ukd = uk[b * 512 + g * 16 + d];
  float s = (s0 + eqc * ukd + uqc * ekd + 4096.f * eqc * ekd) * 0.04419417382415922f;
  float m = s;
  for (int off = 8; off; off >>= 1) m = fmaxf(m, __shfl_xor(m, off));
  float p = expf(s - m);
  float sum = p;
  for (int off = 8; off; off >>= 1) sum += __shfl_xor(sum, off);
  at[c][d] = p / sum;
  __syncthreads();

  const float* Wvb = wv + (long)g * 16 * 512;
  for (int t = tid; t < 16 * 128; t += 256) {
    int r = t >> 7, q = t & 127;
    *(float4*)&Wl[r * 516 + q * 4] = *(const float4*)(Wvb + r * 512 + q * 4);
  }
  __syncthreads();

  for (int t = 0; t < 32; ++t) {
    int flat = t * 256 + tid;
    int cc = flat >> 9, e = flat & 511;
    float a2 = 0.f;
    #pragma unroll
    for (int dd = 0; dd < 16; ++dd) a2 += at[cc][dd] * Wl[dd * 516 + e];
    Pl[cc * 516 + e] = a2;
  }
  if (tid < 16) {
    float o2 = 0.f;
    #pragma unroll
    for (int dd = 0; dd < 16; ++dd) o2 += at[tid][dd] * hv[b * 512 + g * 16 + dd];
    oc[b * 512 + g * 16 + tid] = o2;
  }
  __syncthreads();
  for (int t = 0; t < 32; ++t) {
    int flat = t * 256 + tid;
    int cc = flat & 15, e = flat >> 4;
    UT[(long)b * 262144 + e * 512 + g * 16 + cc] = f2bf(Pl[cc * 516 + e]);
  }
}

// ---------------------------------------------------------------------------
// Kernel 7: c3 = (I+Wp)*oc + bp.
// ---------------------------------------------------------------------------
__global__ __launch_bounds__(256) void k_c3(const float* __restrict__ wp,
    const float* __restrict__ bp, const float* __restrict__ oc,
    float* __restrict__ c3)
{
  int b = blockIdx.x >> 1;
  int o = (blockIdx.x & 1) * 256 + threadIdx.x;
  __shared__ float ov[512];
  for (int i = threadIdx.x; i < 512; i += 256) ov[i] = oc[b * 512 + i];
  __syncthreads();
  const float* wr = wp + (long)o * 512;
  float s = 0.f;
  for (int e = 0; e < 512; e += 4) {
    float4 w4 = *(const float4*)(wr + e);
    s += w4.x * ov[e] + w4.y * ov[e + 1] + w4.z * ov[e + 2] + w4.w * ov[e + 3];
  }
  c3[b * 512 + o] = oc[b * 512 + o] + s + bp[o];
}

// ---------------------------------------------------------------------------
extern "C" void kernel_launch(void* const* d_in, const int* in_sizes, int n_in,
                              void* d_out, int out_size, void* d_ws, size_t ws_size,
                              hipStream_t stream)
{
  (void)in_sizes; (void)n_in; (void)out_size; (void)ws_size;
  const float* x   = (const float*)d_in[0];
  const float* gnw = (const float*)d_in[1];
  const float* gnb = (const float*)d_in[2];
  const float* wq  = (const float*)d_in[3];
  const float* bq  = (const float*)d_in[4];
  const float* wk  = (const float*)d_in[5];
  const float* bk  = (const float*)d_in[6];
  const float* wv  = (const float*)d_in[7];
  const float* bv  = (const float*)d_in[8];
  const float* wp  = (const float*)d_in[9];
  const float* bp  = (const float*)d_in[10];
  float* out = (float*)d_out;

  char* ws = (char*)d_ws;
  u16* xT  = (u16*)ws;  ws += (size_t)16 * 4096 * 512 * 2;  // 64 MB
  u16* Gp  = (u16*)ws;  ws += (size_t)16 * 512 * 512 * 2;   // 8 MB
  float* P = (float*)ws; ws += (size_t)16 * 512 * 512 * 4;  // 16 MB
  u16* UT  = (u16*)ws;  ws += (size_t)16 * 512 * 512 * 2;   // 8 MB
  u16* W3  = (u16*)ws;  ws += (size_t)16 * 512 * 512 * 2;   // 8 MB
  u16* wqb = (u16*)ws;  ws += (size_t)512 * 512 * 2;
  u16* wpI = (u16*)ws;  ws += (size_t)512 * 512 * 2;
  float* a  = (float*)ws; ws += 16 * 512 * 4;
  float* cv = (float*)ws; ws += 16 * 512 * 4;
  float* sx = (float*)ws; ws += 16 * 512 * 4;
  float* eq = (float*)ws; ws += 16 * 512 * 4;
  float* uq = (float*)ws; ws += 16 * 512 * 4;
  float* ek = (float*)ws; ws += 16 * 512 * 4;
  float* uk = (float*)ws; ws += 16 * 512 * 4;
  float* hv = (float*)ws; ws += 16 * 512 * 4;
  float* oc = (float*)ws; ws += 16 * 512 * 4;
  float* c3 = (float*)ws; ws += 16 * 512 * 4;

  u16* xb = (u16*)d_out;                            // d_out[0..64MB): x_bf16
  float* part = (float*)((char*)d_out + 67108864);  // d_out[64..104MB): partials

  k_stats<<<512, 256, 0, stream>>>(x, gnw, gnb, xb, a, cv, sx);
  // combo (transpose-first): transpose(8192) + vec(80) + wconv(1024) + gram(640)
  k_combo<<<9936, 256, 0, stream>>>(xb, part, xT,
                                    wq, bq, wk, bk, wv, bv, wp,
                                    a, cv, sx, wqb, wpI,
                                    eq, uq, ek, uk, hv);
  k_gram_reduce<<<dim3(10, 16), 512, 0, stream>>>(part, a, Gp);
  // P = Wq @ G'  (fp32 out; uses G' symmetry for NT layout)
  k_ntgemm64<1><<<dim3(64, 16), 256, 0, stream>>>(
      wqb, 0, 512, Gp, 262144, 512,
      P, 262144, 512, nullptr, 0, 0, nullptr);
  k_scores<<<512, 256, 0, stream>>>(P, wk, wv, eq, uq, ek, uk, hv, UT, oc);
  k_c3<<<32, 256, 0, stream>>>(wp, bp, oc, c3);
  // W3 = (I+Wp) @ U * D_a  (bf16; A = wpI, B = UT)
  k_ntgemm64<2><<<dim3(64, 16), 256, 0, stream>>>(
      wpI, 0, 512, UT, 262144, 512,
      nullptr, 0, 0, W3, 262144, 512, a);
  // out = W3 @ x + c3  (256^2 tile)
  k_final<<<dim3(32, 16), 512, 0, stream>>>(W3, xT, c3, out);
}